// Round 4
// baseline (1740.829 us; speedup 1.0000x reference)
//
#include <hip/hip_runtime.h>

#define T_STEPS 20
#define NB      64
#define CIN     12
#define LLEN    4096
#define C1N     64
#define C2N     64
#define TL      128
#define NTHR    512          // 8 waves; conv2: wc=wv&3 (c2-tile), wl=wv>>2 (l-half); conv1: m-tile = wv
#define NT2     256
#define XPITCH  20           // ushorts per x-plane row; 10 dwords -> b64 reads conflict-free
#define XROWSA  148          // rows 0..131 live x, 132..147 zeroed (mt=8 A-reads reach 145)
#define S1PITCH 72           // 36 dwords -> 2-way (free) on b128 reads
#define S1ROWS  130

// ---- ws layout (bytes) ----
#define POOL_OFF_F  0                         // float[64*64]
#define W1BF_OFF_B  (NB * C2N * 4)            // ushort [h 2][chunk 2][c1 64][k 32] = 16 KB
#define W2BF_OFF_B  (W1BF_OFF_B + 16384)      // ushort [h 2][dk 3][c2 64][ci 64] = 48 KB
#define XT_OFF_B    (1u << 20)                // packed (hi<<16|lo) [b][ci][t][l]
#define XT_BYTES    ((size_t)NB * CIN * T_STEPS * LLEN * 4)
#define WS_NEED_B   ((size_t)XT_OFF_B + XT_BYTES)

using bf16x8 = __attribute__((ext_vector_type(8))) short;
using s16x4  = __attribute__((ext_vector_type(4))) short;
using f32x4  = __attribute__((ext_vector_type(4))) float;

union ABfrag { bf16x8 v8; s16x4 h[2]; };

__device__ inline unsigned short f32_to_bf16_rne(float f) {
    unsigned u = __builtin_bit_cast(unsigned, f);
    return (unsigned short)((u + 0x7FFFu + ((u >> 16) & 1u)) >> 16);
}

// ---------------------------------------------------------------------------
// Weight prep.
// w1 -> [h][chunk][c1][k32] bf16 hi/lo, k = dk*16+ci for chunk0 (dk 0,1),
//       chunk1 = dk2 in k<16, zero elsewhere (zero-padding lives on B side).
// w2 -> [h][dk][c2][ci] bf16 hi/lo (round-3 verified layout).
// ---------------------------------------------------------------------------
__global__ __launch_bounds__(NT2) void prep_weights(
    const float* __restrict__ w1, const float* __restrict__ w2,
    char* __restrict__ wsb)
{
    int i = blockIdx.x * NT2 + threadIdx.x;
    unsigned short* w1b = (unsigned short*)(wsb + W1BF_OFF_B);
    unsigned short* w2b = (unsigned short*)(wsb + W2BF_OFF_B);
    if (i < 2 * 2 * 64 * 32) {                 // [h][chunk][c1][k]
        int k = i & 31, c1 = (i >> 5) & 63, c = (i >> 11) & 1, h = i >> 12;
        int dk = (c == 0) ? (k >> 4) : 2;
        int ci = (c == 0) ? (k & 15) : k;
        float w = 0.f;
        if (ci < CIN && (c == 0 || k < 16)) w = w1[(c1 * CIN + ci) * 3 + dk];
        unsigned short hi = f32_to_bf16_rne(w);
        float hif = __builtin_bit_cast(float, (unsigned)hi << 16);
        unsigned short lo = f32_to_bf16_rne(w - hif);
        w1b[i] = h ? lo : hi;
    }
    if (i < C2N * C1N * 3) {
        int dk = i % 3, rem = i / 3;
        int ci = rem % C1N, c2 = rem / C1N;
        float w = w2[i];
        unsigned short hi = f32_to_bf16_rne(w);
        float hif = __builtin_bit_cast(float, (unsigned)hi << 16);
        unsigned short lo = f32_to_bf16_rne(w - hif);
        w2b[((0 * 3 + dk) * C2N + c2) * C1N + ci] = hi;
        w2b[((1 * 3 + dk) * C2N + c2) * C1N + ci] = lo;
    }
}

// ---------------------------------------------------------------------------
// x [b][ci][l][t] fp32 -> xt [b][ci][t][l] packed (bf16hi<<16 | bf16lo).
// Register-blocked, no LDS: thread owns one l, reads its 20 t contiguously
// (float4; bytes fully consumed within the wave -> L1 coalesces), writes
// 20 coalesced dword stores. Conversion done here, off snn_main's clock.
// ---------------------------------------------------------------------------
__global__ __launch_bounds__(NT2) void transpose_x(
    const float* __restrict__ xg, unsigned* __restrict__ xt)
{
    const int l   = blockIdx.x * NT2 + threadIdx.x;
    const int bci = blockIdx.y;
    const float4* src = (const float4*)(xg + ((size_t)bci * LLEN + l) * T_STEPS);
    float4 tmp[5];
#pragma unroll
    for (int k = 0; k < 5; ++k) tmp[k] = src[k];
    const float* v = (const float*)tmp;
    unsigned* dst = xt + (size_t)bci * T_STEPS * LLEN + l;
#pragma unroll
    for (int t = 0; t < T_STEPS; ++t) {
        float f = v[t];
        unsigned short hi = f32_to_bf16_rne(f);
        float hif = __builtin_bit_cast(float, (unsigned)hi << 16);
        unsigned short lo = f32_to_bf16_rne(f - hif);
        dst[(size_t)t * LLEN] = ((unsigned)hi << 16) | (unsigned)lo;
    }
}

// ---------------------------------------------------------------------------
// Main kernel: BOTH convs on MFMA. conv1: A = x (hi/lo planes in LDS),
// B = w1 hi/lo from global (L1-resident), 3-product exact-enough split;
// m-tile = wave id so A-frags are shared across all 4 n-tiles.
// conv2: unchanged round-3 structure (verified absmax 0.0).
// Single x-buffer: phase1 reads x(t) / writes s1; B1; phase2 reads s1,
// writes x(t+1), prefetches x(t+2); B2.
// ---------------------------------------------------------------------------
__global__ __launch_bounds__(NTHR, 4) void snn_main(
    const float* __restrict__ xg, const unsigned* __restrict__ xt, int use_xt,
    const float* __restrict__ b1g, const float* __restrict__ b2g,
    const float* __restrict__ gp, const float* __restrict__ t1p,
    const float* __restrict__ t2p,
    const char* __restrict__ wsb, float* __restrict__ pooled)
{
    __shared__ __align__(16) unsigned short xhi[XROWSA * XPITCH];
    __shared__ __align__(16) unsigned short xlo[XROWSA * XPITCH];
    __shared__ __align__(16) unsigned short s1t[S1ROWS * S1PITCH];

    const int tid  = threadIdx.x;
    const int lane = tid & 63;
    const int wv   = __builtin_amdgcn_readfirstlane(tid >> 6);
    const int wc   = wv & 3, wl = wv >> 2;
    const int cb   = wc * 16;
    const int b    = blockIdx.y;
    const int l0   = blockIdx.x * TL;

    const float gain = gp[0], th1 = t1p[0], th2 = t2p[0];
    const unsigned short* __restrict__ w1b = (const unsigned short*)(wsb + W1BF_OFF_B);
    const unsigned short* __restrict__ w2b = (const unsigned short*)(wsb + W2BF_OFF_B);

    const int m16 = lane & 15;
    const int q   = lane >> 4;          // quad 0..3
    const int oct = (q & 1) * 8;        // A-frag ci octet
    const int dk0 = q >> 1;             // chunk0 dk for this quad

    // conv2 B-fragments (round-3 verified layout) — compiler parks in AGPRs
    bf16x8 bw[2][3][2];
    {
        int c2 = cb + m16, ci0 = q * 8;
#pragma unroll
        for (int h = 0; h < 2; ++h)
#pragma unroll
            for (int dk = 0; dk < 3; ++dk)
#pragma unroll
                for (int cc = 0; cc < 2; ++cc)
                    bw[h][dk][cc] = *(const bf16x8*)
                        (w2b + (((h * 3 + dk) * C2N + c2) * C1N + cc * 32 + ci0));
    }
    const float b2v = b2g[cb + m16];

    // conv1 per-lane thresholds (bias folded): spike <=> D >= th1/gain - b1[c1]
    float thr1[4];
#pragma unroll
    for (int nt = 0; nt < 4; ++nt) thr1[nt] = th1 / gain - b1g[nt * 16 + m16];

    float v2s[4][4], accs[4][4];
#pragma unroll
    for (int lt = 0; lt < 4; ++lt)
#pragma unroll
        for (int r = 0; r < 4; ++r) { v2s[lt][r] = 0.f; accs[lt][r] = 0.f; }

    // ---- one-time zero of plane pads (cols 12..19 all rows; rows 132..147) ----
    for (int i = tid; i < XROWSA * 8; i += NTHR) {
        int p = i >> 3, c = 12 + (i & 7);
        xhi[p * XPITCH + c] = 0; xlo[p * XPITCH + c] = 0;
    }
    for (int i = tid; i < 16 * CIN; i += NTHR) {
        int p = 132 + i / CIN, c = i % CIN;
        xhi[p * XPITCH + c] = 0; xlo[p * XPITCH + c] = 0;
    }

    // ---- staging setup: 1584 elems, 4 strided chunks/thread ----
    const unsigned* __restrict__ srcu =
        use_xt ? (xt + (size_t)b * CIN * T_STEPS * LLEN)
               : (const unsigned*)(xg + (size_t)b * CIN * LLEN * T_STEPS);
    const size_t tstep = use_xt ? (size_t)LLEN : (size_t)1;

    size_t off[4]; int lpos[4]; bool ldok[4], gok[4]; unsigned pf[4];
#pragma unroll
    for (int k = 0; k < 4; ++k) {
        int e = tid + k * NTHR;
        bool w = e < CIN * 132;
        int ev = w ? e : 0;
        int ci = ev / 132, p = ev - ci * 132;
        int gl = l0 - 2 + p;
        bool g = w && ((unsigned)gl < (unsigned)LLEN);
        int glc = g ? gl : 0;
        off[k]  = use_xt ? ((size_t)ci * T_STEPS * LLEN + glc)
                         : ((size_t)ci * LLEN + glc) * T_STEPS;
        lpos[k] = p * XPITCH + ci;
        ldok[k] = w; gok[k] = g;
    }

    auto stage_write = [&](int k) {
        unsigned pv = pf[k], hi, lo;
        if (use_xt) { hi = pv >> 16; lo = pv & 0xFFFFu; }
        else {
            float f = __builtin_bit_cast(float, pv);
            hi = f32_to_bf16_rne(f);
            float hif = __builtin_bit_cast(float, hi << 16);
            lo = f32_to_bf16_rne(f - hif);
        }
        xhi[lpos[k]] = (unsigned short)hi;
        xlo[lpos[k]] = (unsigned short)lo;
    };

    // preamble: stage x(0); prefetch x(1)
#pragma unroll
    for (int k = 0; k < 4; ++k) pf[k] = gok[k] ? srcu[off[k]] : 0u;
#pragma unroll
    for (int k = 0; k < 4; ++k) if (ldok[k]) stage_write(k);
#pragma unroll
    for (int k = 0; k < 4; ++k) pf[k] = gok[k] ? srcu[off[k] + tstep] : 0u;
    __syncthreads();

#pragma unroll 1
    for (int t = 0; t < T_STEPS; ++t) {
        // ================= phase 1: conv1 on MFMA =================
        {
            // A-fragments for m-tile = wv (shared by all 4 n-tiles)
            int pc0 = (wv * 16 + m16 + dk0) * XPITCH + oct;  // chunk0: dk = q>>1
            int pc1 = (wv * 16 + m16 + 2)   * XPITCH + oct;  // chunk1: dk = 2
            ABfrag ah0, al0, ah1, al1;
            ah0.h[0] = *(const s16x4*)&xhi[pc0]; ah0.h[1] = *(const s16x4*)&xhi[pc0 + 4];
            al0.h[0] = *(const s16x4*)&xlo[pc0]; al0.h[1] = *(const s16x4*)&xlo[pc0 + 4];
            ah1.h[0] = *(const s16x4*)&xhi[pc1]; ah1.h[1] = *(const s16x4*)&xhi[pc1 + 4];
            al1.h[0] = *(const s16x4*)&xlo[pc1]; al1.h[1] = *(const s16x4*)&xlo[pc1 + 4];
#pragma unroll
            for (int nt = 0; nt < 4; ++nt) {
                int c1n = nt * 16 + m16;
                const unsigned short* wb = w1b + (size_t)c1n * 32 + q * 8;
                bf16x8 bh0 = *(const bf16x8*)(wb + 0 * 2048);
                bf16x8 bh1 = *(const bf16x8*)(wb + 1 * 2048);
                bf16x8 bl0 = *(const bf16x8*)(wb + 2 * 2048);
                bf16x8 bl1 = *(const bf16x8*)(wb + 3 * 2048);
                f32x4 d = {0.f, 0.f, 0.f, 0.f};
                d = __builtin_amdgcn_mfma_f32_16x16x32_bf16(ah0.v8, bh0, d, 0, 0, 0);
                d = __builtin_amdgcn_mfma_f32_16x16x32_bf16(al0.v8, bh0, d, 0, 0, 0);
                d = __builtin_amdgcn_mfma_f32_16x16x32_bf16(ah0.v8, bl0, d, 0, 0, 0);
                d = __builtin_amdgcn_mfma_f32_16x16x32_bf16(ah1.v8, bh1, d, 0, 0, 0);
                d = __builtin_amdgcn_mfma_f32_16x16x32_bf16(al1.v8, bh1, d, 0, 0, 0);
                d = __builtin_amdgcn_mfma_f32_16x16x32_bf16(ah1.v8, bl1, d, 0, 0, 0);
                int rowb = wv * 16 + q * 4;          // s1t row for reg r: rowb+r (<=127+... always <130 here)
                int glb  = l0 - 1 + rowb;
#pragma unroll
                for (int r = 0; r < 4; ++r) {
                    bool inL = (unsigned)(glb + r) < (unsigned)LLEN;
                    unsigned short sv = (inL && (d[r] >= thr1[nt])) ? (unsigned short)0x3F80u
                                                                    : (unsigned short)0;
                    s1t[(rowb + r) * S1PITCH + c1n] = sv;
                }
            }
        }
        // extra m-tile 8 (s1 rows 128,129) on waves 0..3 (nt = wv)
        if (wv < 4) {
            int pc0 = (128 + m16 + dk0) * XPITCH + oct;
            int pc1 = (128 + m16 + 2)   * XPITCH + oct;
            ABfrag ah0, al0, ah1, al1;
            ah0.h[0] = *(const s16x4*)&xhi[pc0]; ah0.h[1] = *(const s16x4*)&xhi[pc0 + 4];
            al0.h[0] = *(const s16x4*)&xlo[pc0]; al0.h[1] = *(const s16x4*)&xlo[pc0 + 4];
            ah1.h[0] = *(const s16x4*)&xhi[pc1]; ah1.h[1] = *(const s16x4*)&xhi[pc1 + 4];
            al1.h[0] = *(const s16x4*)&xlo[pc1]; al1.h[1] = *(const s16x4*)&xlo[pc1 + 4];
            int nt = wv;
            int c1n = nt * 16 + m16;
            const unsigned short* wb = w1b + (size_t)c1n * 32 + q * 8;
            bf16x8 bh0 = *(const bf16x8*)(wb + 0 * 2048);
            bf16x8 bh1 = *(const bf16x8*)(wb + 1 * 2048);
            bf16x8 bl0 = *(const bf16x8*)(wb + 2 * 2048);
            bf16x8 bl1 = *(const bf16x8*)(wb + 3 * 2048);
            f32x4 d = {0.f, 0.f, 0.f, 0.f};
            d = __builtin_amdgcn_mfma_f32_16x16x32_bf16(ah0.v8, bh0, d, 0, 0, 0);
            d = __builtin_amdgcn_mfma_f32_16x16x32_bf16(al0.v8, bh0, d, 0, 0, 0);
            d = __builtin_amdgcn_mfma_f32_16x16x32_bf16(ah0.v8, bl0, d, 0, 0, 0);
            d = __builtin_amdgcn_mfma_f32_16x16x32_bf16(ah1.v8, bh1, d, 0, 0, 0);
            d = __builtin_amdgcn_mfma_f32_16x16x32_bf16(al1.v8, bh1, d, 0, 0, 0);
            d = __builtin_amdgcn_mfma_f32_16x16x32_bf16(ah1.v8, bl1, d, 0, 0, 0);
            float thr = thr1[0];
            thr = (nt == 1) ? thr1[1] : thr;
            thr = (nt == 2) ? thr1[2] : thr;
            thr = (nt == 3) ? thr1[3] : thr;
            int rowb = 128 + q * 4;
            int glb  = l0 - 1 + rowb;
#pragma unroll
            for (int r = 0; r < 4; ++r) {
                int row = rowb + r;
                if (row < S1ROWS) {
                    bool inL = (unsigned)(glb + r) < (unsigned)LLEN;
                    unsigned short sv = (inL && (d[r] >= thr)) ? (unsigned short)0x3F80u
                                                               : (unsigned short)0;
                    s1t[row * S1PITCH + c1n] = sv;
                }
            }
        }
        __syncthreads();

        // ============ phase 2: staging (early) + conv2 + LIF ============
        if (t < T_STEPS - 1) {
#pragma unroll
            for (int k = 0; k < 4; ++k) if (ldok[k]) stage_write(k);
            if (t < T_STEPS - 2) {
#pragma unroll
                for (int k = 0; k < 4; ++k)
                    pf[k] = gok[k] ? srcu[off[k] + (size_t)(t + 2) * tstep] : 0u;
            }
        }
#pragma unroll
        for (int lt = 0; lt < 4; ++lt) {
            f32x4 d = {0.f, 0.f, 0.f, 0.f};
#pragma unroll
            for (int dk = 0; dk < 3; ++dk) {
                int row = wl * 64 + lt * 16 + m16 + dk;
#pragma unroll
                for (int cc = 0; cc < 2; ++cc) {
                    bf16x8 a = *(const bf16x8*)&s1t[row * S1PITCH + cc * 32 + q * 8];
                    d = __builtin_amdgcn_mfma_f32_16x16x32_bf16(a, bw[0][dk][cc], d, 0, 0, 0);
                    d = __builtin_amdgcn_mfma_f32_16x16x32_bf16(a, bw[1][dk][cc], d, 0, 0, 0);
                }
            }
#pragma unroll
            for (int r = 0; r < 4; ++r) {
                float i2 = (d[r] + b2v) * gain;
                float v  = v2s[lt][r] + (i2 - v2s[lt][r]) * (1.0f / 0.9f);
                bool  sp = v >= th2;
                v2s[lt][r]   = sp ? 0.f : v;
                accs[lt][r] += sp ? 1.f : 0.f;
            }
        }
        __syncthreads();
    }

    // ---- reduce acc over l; lanes L, L+16, L+32, L+48 share c2 ----
    float s = 0.f;
#pragma unroll
    for (int lt = 0; lt < 4; ++lt)
#pragma unroll
        for (int r = 0; r < 4; ++r) s += accs[lt][r];
    s += __shfl_down(s, 32, 64);
    s += __shfl_down(s, 16, 64);
    if (lane < 16) atomicAdd(&pooled[b * C2N + cb + lane], s);
}

__global__ __launch_bounds__(NT2) void fc_kernel(
    const float* __restrict__ pooled, const float* __restrict__ fcw,
    const float* __restrict__ fcb, float* __restrict__ out)
{
    int i = threadIdx.x, b = i >> 2, cls = i & 3;
    float s = 0.f;
#pragma unroll 8
    for (int c = 0; c < C2N; ++c)
        s += pooled[b * C2N + c] * fcw[cls * C2N + c];
    out[b * 4 + cls] = s * (1.0f / ((float)T_STEPS * (float)LLEN)) + fcb[cls];
}

extern "C" void kernel_launch(void* const* d_in, const int* in_sizes, int n_in,
                              void* d_out, int out_size, void* d_ws, size_t ws_size,
                              hipStream_t stream)
{
    const float* xg  = (const float*)d_in[0];
    const float* w1  = (const float*)d_in[1];
    const float* b1  = (const float*)d_in[2];
    const float* w2  = (const float*)d_in[3];
    const float* b2  = (const float*)d_in[4];
    const float* gp  = (const float*)d_in[5];
    const float* t1  = (const float*)d_in[6];
    const float* t2  = (const float*)d_in[7];
    const float* fcw = (const float*)d_in[8];
    const float* fcb = (const float*)d_in[9];
    char*  wsb = (char*)d_ws;
    float* out = (float*)d_out;

    const int use_xt = (ws_size >= WS_NEED_B) ? 1 : 0;
    unsigned* xt = (unsigned*)(wsb + XT_OFF_B);

    hipMemsetAsync(wsb + POOL_OFF_F, 0, NB * C2N * sizeof(float), stream);
    prep_weights<<<(C2N * C1N * 3 + NT2 - 1) / NT2, NT2, 0, stream>>>(w1, w2, wsb);
    if (use_xt)
        transpose_x<<<dim3(LLEN / NT2, NB * CIN), NT2, 0, stream>>>(xg, xt);
    snn_main<<<dim3(LLEN / TL, NB), NTHR, 0, stream>>>(
        xg, xt, use_xt, b1, b2, gp, t1, t2, wsb, (float*)(wsb + POOL_OFF_F));
    fc_kernel<<<1, NT2, 0, stream>>>((const float*)(wsb + POOL_OFF_F), fcw, fcb, out);
}